// Round 2
// baseline (233.376 us; speedup 1.0000x reference)
//
#include <hip/hip_runtime.h>
#include <hip/hip_bf16.h>
#include <math.h>

#define CHANNEL 128
#define NEG_INF (-1e30f)

// --- precompute P2[r] = (W W^T relw[r]^T)/16 and rel_norm[r] = ||relw[r]||^2 ---
// grid = R, block = CHANNEL
__global__ void prep_kernel(const float* __restrict__ relw, const float* __restrict__ W,
                            float* __restrict__ P2, float* __restrict__ rel_norm) {
    __shared__ float rw[CHANNEL];
    __shared__ float kr[CHANNEL];
    __shared__ float red[CHANNEL];
    int j = blockIdx.x;
    int c = threadIdx.x;
    float v = relw[j * CHANNEL + c];
    rw[c] = v;
    red[c] = v * v;
    __syncthreads();
    for (int s = CHANNEL / 2; s > 0; s >>= 1) {
        if (c < s) red[c] += red[c + s];
        __syncthreads();
    }
    if (c == 0) rel_norm[j] = red[0];
    float acc = 0.f;
    for (int k = 0; k < CHANNEL; ++k) acc += rw[k] * W[k * CHANNEL + c];
    kr[c] = acc;
    __syncthreads();
    float acc2 = 0.f;
    for (int cc = 0; cc < CHANNEL; ++cc) acc2 += W[c * CHANNEL + cc] * kr[cc];
    P2[j * CHANNEL + c] = acc2 * 0.0625f;
}

__global__ void deg_count_kernel(const int* __restrict__ eidx, int* __restrict__ deg, int E) {
    int e = blockIdx.x * blockDim.x + threadIdx.x;
    if (e < E) atomicAdd(deg + eidx[e], 1);
}

// single block of 1024 threads: exclusive scan of deg[N] -> rowptr[N+1], cursor[N]
__global__ void scan_kernel(const int* __restrict__ deg, int* __restrict__ rowptr,
                            int* __restrict__ cursor, int N, int E) {
    __shared__ int part[1024];
    int t = threadIdx.x;
    int chunk = (N + 1023) / 1024;
    int lo = t * chunk;
    int hi = lo + chunk; if (hi > N) hi = N;
    int s = 0;
    for (int i = lo; i < hi; ++i) s += deg[i];
    part[t] = s;
    __syncthreads();
    for (int off = 1; off < 1024; off <<= 1) {
        int v = 0;
        if (t >= off) v = part[t - off];
        __syncthreads();
        if (t >= off) part[t] += v;
        __syncthreads();
    }
    int run = part[t] - s;   // exclusive base for this chunk
    for (int i = lo; i < hi; ++i) {
        rowptr[i] = run;
        cursor[i] = run;
        run += deg[i];
    }
    if (t == 0) rowptr[N] = E;
}

// bin edges by head: recs[pos] = { tail | (type<<20), edge_id }
__global__ void scatter_kernel(const int* __restrict__ eidx, const int* __restrict__ etype,
                               int* __restrict__ cursor, int2* __restrict__ recs, int E) {
    int e = blockIdx.x * blockDim.x + threadIdx.x;
    if (e >= E) return;
    int h = eidx[e];
    int t = eidx[E + e];
    int r = etype[e] - 1;
    int pos = atomicAdd(cursor + h, 1);
    recs[pos] = make_int2(t | (r << 20), e);
}

// one wave per head: fused dots + double segment-softmax, all reductions in-register
__global__ void __launch_bounds__(256) main_kernel(
        const float* __restrict__ ent, const float* __restrict__ P2,
        const float* __restrict__ rel_norm, const int* __restrict__ rowptr,
        const int2* __restrict__ recs, float2* __restrict__ sc,
        float* __restrict__ out, int N) {
    int wid = (int)((blockIdx.x * blockDim.x + threadIdx.x) >> 6);
    if (wid >= N) return;
    int lane = threadIdx.x & 63;
    int group = lane >> 4;
    int sub = lane & 15;

    int start = rowptr[wid];
    int deg = rowptr[wid + 1] - start;
    if (deg == 0) return;

    const float4* hp = (const float4*)(ent + (size_t)wid * CHANNEL);
    float4 h0 = hp[sub], h1 = hp[sub + 16];

    // sweep 1: per-edge dots (16 lanes/edge, 4 edges per wave-iter), online max of d2
    float pm1 = NEG_INF;
    for (int k0 = 0; k0 < deg; k0 += 4) {
        int idx = k0 + group;
        bool act = idx < deg;
        int j = start + (act ? idx : 0);
        int2 rc = recs[j];
        float d1 = 0.f, d2 = 0.f;
        if (act) {
            int tail = rc.x & 0xFFFFF;
            int typ = rc.x >> 20;
            const float4* tp = (const float4*)(ent + (size_t)tail * CHANNEL);
            const float4* rp = (const float4*)(P2 + typ * CHANNEL);
            float4 t0 = tp[sub], t1 = tp[sub + 16];
            float4 r0 = rp[sub], r1 = rp[sub + 16];
            d1 = h0.x * t0.x + h0.y * t0.y + h0.z * t0.z + h0.w * t0.w
               + h1.x * t1.x + h1.y * t1.y + h1.z * t1.z + h1.w * t1.w;
            d2 = h0.x * r0.x + h0.y * r0.y + h0.z * r0.z + h0.w * r0.w
               + h1.x * r1.x + h1.y * r1.y + h1.z * r1.z + h1.w * r1.w;
        }
#pragma unroll
        for (int m = 1; m <= 8; m <<= 1) {
            d1 += __shfl_xor(d1, m);
            d2 += __shfl_xor(d2, m);
        }
        if (act) {
            if (sub == 0) sc[j] = make_float2(d1, d2);
            pm1 = fmaxf(pm1, d2);
        }
    }
    pm1 = fmaxf(pm1, __shfl_xor(pm1, 16));
    pm1 = fmaxf(pm1, __shfl_xor(pm1, 32));
    float m1 = pm1;

    // sweep 2: s1 = sum exp(d2 - m1)
    float s1 = 0.f;
    for (int k = lane; k < deg; k += 64) s1 += expf(sc[start + k].y - m1);
#pragma unroll
    for (int m = 32; m; m >>= 1) s1 += __shfl_xor(s1, m);

    // sweep 3: st = d1 + rs^2 * rel_norm, online max
    float pm2 = NEG_INF;
    for (int k = lane; k < deg; k += 64) {
        float2 v = sc[start + k];
        int typ = recs[start + k].x >> 20;
        float e1 = expf(v.y - m1);
        float rs = e1 / s1;
        float stv = v.x + rs * rs * rel_norm[typ];
        sc[start + k].x = stv;
        pm2 = fmaxf(pm2, stv);
    }
#pragma unroll
    for (int m = 32; m; m >>= 1) pm2 = fmaxf(pm2, __shfl_xor(pm2, m));
    float m2 = pm2;

    // sweep 4: s2 = sum exp(st - m2)
    float s2 = 0.f;
    for (int k = lane; k < deg; k += 64) {
        float e2 = expf(sc[start + k].x - m2);
        sc[start + k].y = e2;
        s2 += e2;
    }
#pragma unroll
    for (int m = 32; m; m >>= 1) s2 += __shfl_xor(s2, m);
    float inv = 1.f / s2;

    // sweep 5: scatter normalized scores to original edge order
    for (int k = lane; k < deg; k += 64)
        out[recs[start + k].y] = sc[start + k].y * inv;
}

extern "C" void kernel_launch(void* const* d_in, const int* in_sizes, int n_in,
                              void* d_out, int out_size, void* d_ws, size_t ws_size,
                              hipStream_t stream) {
    const float* ent   = (const float*)d_in[0];
    const float* relw  = (const float*)d_in[2];
    const float* W     = (const float*)d_in[3];
    const int*   eidx  = (const int*)d_in[4];
    const int*   etype = (const int*)d_in[5];
    float* out = (float*)d_out;

    const int E = in_sizes[5];
    const int N = in_sizes[0] / CHANNEL;
    const int R = in_sizes[2] / CHANNEL;

    char* base = (char*)d_ws;
    auto alloc = [&](size_t bytes) {
        char* p = base;
        base += (bytes + 15) & ~(size_t)15;
        return p;
    };
    int*    deg      = (int*)alloc((size_t)N * 4);
    int*    rowptr   = (int*)alloc((size_t)(N + 1) * 4);
    int*    cursor   = (int*)alloc((size_t)N * 4);
    int2*   recs     = (int2*)alloc((size_t)E * 8);
    float2* sc       = (float2*)alloc((size_t)E * 8);
    float*  P2       = (float*)alloc((size_t)R * CHANNEL * 4);
    float*  rel_norm = (float*)alloc((size_t)R * 4);

    hipMemsetAsync(deg, 0, (size_t)N * 4, stream);

    prep_kernel<<<R, CHANNEL, 0, stream>>>(relw, W, P2, rel_norm);

    int be = (E + 255) / 256;
    deg_count_kernel<<<be, 256, 0, stream>>>(eidx, deg, E);
    scan_kernel<<<1, 1024, 0, stream>>>(deg, rowptr, cursor, N, E);
    scatter_kernel<<<be, 256, 0, stream>>>(eidx, etype, cursor, recs, E);

    int bm = (N + 3) / 4;  // 4 waves per block, one wave per head
    main_kernel<<<bm, 256, 0, stream>>>(ent, P2, rel_norm, rowptr, recs, sc, out, N);
}

// Round 3
// 153.110 us; speedup vs baseline: 1.5242x; 1.5242x over previous
//
#include <hip/hip_runtime.h>
#include <hip/hip_bf16.h>
#include <math.h>

#define CHANNEL 128
#define NEG_INF (-1e30f)

// --- precompute P2[r] = (W W^T relw[r]^T)/16 and rel_norm[r] = ||relw[r]||^2 ---
__global__ void prep_kernel(const float* __restrict__ relw, const float* __restrict__ W,
                            float* __restrict__ P2, float* __restrict__ rel_norm) {
    __shared__ float rw[CHANNEL];
    __shared__ float kr[CHANNEL];
    __shared__ float red[CHANNEL];
    int j = blockIdx.x;
    int c = threadIdx.x;
    float v = relw[j * CHANNEL + c];
    rw[c] = v;
    red[c] = v * v;
    __syncthreads();
    for (int s = CHANNEL / 2; s > 0; s >>= 1) {
        if (c < s) red[c] += red[c + s];
        __syncthreads();
    }
    if (c == 0) rel_norm[j] = red[0];
    float acc = 0.f;
    for (int k = 0; k < CHANNEL; ++k) acc += rw[k] * W[k * CHANNEL + c];
    kr[c] = acc;
    __syncthreads();
    float acc2 = 0.f;
    for (int cc = 0; cc < CHANNEL; ++cc) acc2 += W[c * CHANNEL + cc] * kr[cc];
    P2[j * CHANNEL + c] = acc2 * 0.0625f;
}

__global__ void deg_count_kernel(const int* __restrict__ eidx, int* __restrict__ deg, int E) {
    int e = blockIdx.x * blockDim.x + threadIdx.x;
    if (e < E) atomicAdd(deg + eidx[e], 1);
}

// hierarchical scan stage 1: per-block (256) exclusive scan, emit block totals
__global__ void scan1_kernel(const int* __restrict__ deg, int* __restrict__ rowptr,
                             int* __restrict__ partial, int N) {
    __shared__ int sh[256];
    int t = threadIdx.x;
    int i = blockIdx.x * 256 + t;
    int v = (i < N) ? deg[i] : 0;
    sh[t] = v;
    __syncthreads();
    for (int off = 1; off < 256; off <<= 1) {
        int u = (t >= off) ? sh[t - off] : 0;
        __syncthreads();
        sh[t] += u;
        __syncthreads();
    }
    if (i < N) rowptr[i] = sh[t] - v;            // local exclusive
    if (t == 255) partial[blockIdx.x] = sh[255]; // block total
}

// stage 2: single block scans the block totals (nblk <= 1024)
__global__ void scan2_kernel(int* __restrict__ partial, int nblk) {
    __shared__ int sh[1024];
    int t = threadIdx.x;
    int v = (t < nblk) ? partial[t] : 0;
    sh[t] = v;
    __syncthreads();
    for (int off = 1; off < 1024; off <<= 1) {
        int u = (t >= off) ? sh[t - off] : 0;
        __syncthreads();
        sh[t] += u;
        __syncthreads();
    }
    if (t < nblk) partial[t] = sh[t] - v;        // exclusive block offsets
}

// stage 3: add block offsets, produce rowptr + cursor
__global__ void scan3_kernel(int* __restrict__ rowptr, int* __restrict__ cursor,
                             const int* __restrict__ partial, int N, int E) {
    int i = blockIdx.x * 256 + threadIdx.x;
    if (i < N) {
        int v = rowptr[i] + partial[blockIdx.x];
        rowptr[i] = v;
        cursor[i] = v;
    } else if (i == N) {
        rowptr[N] = E;
    }
}

// bin edges by head: recs[pos] = { tail | (type<<20), edge_id }
__global__ void scatter_kernel(const int* __restrict__ eidx, const int* __restrict__ etype,
                               int* __restrict__ cursor, int2* __restrict__ recs, int E) {
    int e = blockIdx.x * blockDim.x + threadIdx.x;
    if (e >= E) return;
    int h = eidx[e];
    int t = eidx[E + e];
    int r = etype[e] - 1;
    int pos = atomicAdd(cursor + h, 1);
    recs[pos] = make_int2(t | (r << 20), e);
}

// one wave per head: fused dots + double segment-softmax, all reductions in-register
__global__ void __launch_bounds__(256) main_kernel(
        const float* __restrict__ ent, const float* __restrict__ P2,
        const float* __restrict__ rel_norm, const int* __restrict__ rowptr,
        const int2* __restrict__ recs, float2* __restrict__ sc,
        float* __restrict__ out, int N) {
    int wid = (int)((blockIdx.x * blockDim.x + threadIdx.x) >> 6);
    if (wid >= N) return;
    int lane = threadIdx.x & 63;
    int group = lane >> 4;
    int sub = lane & 15;

    int start = rowptr[wid];
    int deg = rowptr[wid + 1] - start;
    if (deg == 0) return;

    const float4* hp = (const float4*)(ent + (size_t)wid * CHANNEL);
    float4 h0 = hp[sub], h1 = hp[sub + 16];

    // sweep 1: per-edge dots (16 lanes/edge, 4 edges per wave-iter), online max of d2
    float pm1 = NEG_INF;
    for (int k0 = 0; k0 < deg; k0 += 4) {
        int idx = k0 + group;
        bool act = idx < deg;
        int j = start + (act ? idx : 0);
        int2 rc = recs[j];
        float d1 = 0.f, d2 = 0.f;
        if (act) {
            int tail = rc.x & 0xFFFFF;
            int typ = rc.x >> 20;
            const float4* tp = (const float4*)(ent + (size_t)tail * CHANNEL);
            const float4* rp = (const float4*)(P2 + typ * CHANNEL);
            float4 t0 = tp[sub], t1 = tp[sub + 16];
            float4 r0 = rp[sub], r1 = rp[sub + 16];
            d1 = h0.x * t0.x + h0.y * t0.y + h0.z * t0.z + h0.w * t0.w
               + h1.x * t1.x + h1.y * t1.y + h1.z * t1.z + h1.w * t1.w;
            d2 = h0.x * r0.x + h0.y * r0.y + h0.z * r0.z + h0.w * r0.w
               + h1.x * r1.x + h1.y * r1.y + h1.z * r1.z + h1.w * r1.w;
        }
#pragma unroll
        for (int m = 1; m <= 8; m <<= 1) {
            d1 += __shfl_xor(d1, m);
            d2 += __shfl_xor(d2, m);
        }
        if (act) {
            if (sub == 0) sc[j] = make_float2(d1, d2);
            pm1 = fmaxf(pm1, d2);
        }
    }
    pm1 = fmaxf(pm1, __shfl_xor(pm1, 16));
    pm1 = fmaxf(pm1, __shfl_xor(pm1, 32));
    float m1 = pm1;

    // sweep 2: s1 = sum exp(d2 - m1)
    float s1 = 0.f;
    for (int k = lane; k < deg; k += 64) s1 += expf(sc[start + k].y - m1);
#pragma unroll
    for (int m = 32; m; m >>= 1) s1 += __shfl_xor(s1, m);

    // sweep 3: st = d1 + rs^2 * rel_norm, online max
    float pm2 = NEG_INF;
    for (int k = lane; k < deg; k += 64) {
        float2 v = sc[start + k];
        int typ = recs[start + k].x >> 20;
        float e1 = expf(v.y - m1);
        float rs = e1 / s1;
        float stv = v.x + rs * rs * rel_norm[typ];
        sc[start + k].x = stv;
        pm2 = fmaxf(pm2, stv);
    }
#pragma unroll
    for (int m = 32; m; m >>= 1) pm2 = fmaxf(pm2, __shfl_xor(pm2, m));
    float m2 = pm2;

    // sweep 4: s2 = sum exp(st - m2)
    float s2 = 0.f;
    for (int k = lane; k < deg; k += 64) {
        float e2 = expf(sc[start + k].x - m2);
        sc[start + k].y = e2;
        s2 += e2;
    }
#pragma unroll
    for (int m = 32; m; m >>= 1) s2 += __shfl_xor(s2, m);
    float inv = 1.f / s2;

    // sweep 5: scatter normalized scores to original edge order
    for (int k = lane; k < deg; k += 64)
        out[recs[start + k].y] = sc[start + k].y * inv;
}

extern "C" void kernel_launch(void* const* d_in, const int* in_sizes, int n_in,
                              void* d_out, int out_size, void* d_ws, size_t ws_size,
                              hipStream_t stream) {
    const float* ent   = (const float*)d_in[0];
    const float* relw  = (const float*)d_in[2];
    const float* W     = (const float*)d_in[3];
    const int*   eidx  = (const int*)d_in[4];
    const int*   etype = (const int*)d_in[5];
    float* out = (float*)d_out;

    const int E = in_sizes[5];
    const int N = in_sizes[0] / CHANNEL;
    const int R = in_sizes[2] / CHANNEL;

    char* base = (char*)d_ws;
    auto alloc = [&](size_t bytes) {
        char* p = base;
        base += (bytes + 15) & ~(size_t)15;
        return p;
    };
    int*    deg      = (int*)alloc((size_t)N * 4);
    int*    rowptr   = (int*)alloc((size_t)(N + 1) * 4);
    int*    cursor   = (int*)alloc((size_t)N * 4);
    int*    partial  = (int*)alloc(1024 * 4);
    int2*   recs     = (int2*)alloc((size_t)E * 8);
    float2* sc       = (float2*)alloc((size_t)E * 8);
    float*  P2       = (float*)alloc((size_t)R * CHANNEL * 4);
    float*  rel_norm = (float*)alloc((size_t)R * 4);

    hipMemsetAsync(deg, 0, (size_t)N * 4, stream);

    prep_kernel<<<R, CHANNEL, 0, stream>>>(relw, W, P2, rel_norm);

    int be = (E + 255) / 256;
    deg_count_kernel<<<be, 256, 0, stream>>>(eidx, deg, E);

    int nblk = (N + 255) / 256;  // 157 for N=40000; must be <= 1024
    scan1_kernel<<<nblk, 256, 0, stream>>>(deg, rowptr, partial, N);
    scan2_kernel<<<1, 1024, 0, stream>>>(partial, nblk);
    scan3_kernel<<<(N + 256) / 256, 256, 0, stream>>>(rowptr, cursor, partial, N, E);

    scatter_kernel<<<be, 256, 0, stream>>>(eidx, etype, cursor, recs, E);

    int bm = (N + 3) / 4;  // 4 waves per block, one wave per head
    main_kernel<<<bm, 256, 0, stream>>>(ent, P2, rel_norm, rowptr, recs, sc, out, N);
}